// Round 15
// baseline (114.254 us; speedup 1.0000x reference)
//
#include <hip/hip_runtime.h>
#include <hip/hip_bf16.h>

typedef unsigned short u16;
typedef unsigned int u32;
typedef __attribute__((ext_vector_type(8))) __bf16 bf16x8;
typedef __attribute__((ext_vector_type(4))) float f32x4;
typedef __attribute__((ext_vector_type(4))) u16 u16x4;
typedef __attribute__((ext_vector_type(8))) u16 u16x8;
typedef __attribute__((ext_vector_type(4))) u32 u32x4;

__device__ __forceinline__ u16 f2bf(float f) {
  return __builtin_bit_cast(u16, (__bf16)f);  // native RNE cvt
}

__device__ __forceinline__ void gload_lds16(const void* g, void* l) {
  __builtin_amdgcn_global_load_lds((const __attribute__((address_space(1))) void*)g,
                                   (__attribute__((address_space(3))) void*)l, 16, 0, 0);
}

// ---------------- fused prep: fp32->bf16 cvt of x + both weight transposes ----------------
__global__ __launch_bounds__(256) void prep_kernel(const float* __restrict__ x, u16* __restrict__ xb,
                                                   const float* __restrict__ wq, u16* __restrict__ wqT,
                                                   const float* __restrict__ wp, u16* __restrict__ wpT) {
  const int bid = blockIdx.x;
  const int tid = threadIdx.x;
  if (bid < 4096) {  // cvt x
    const int i = (bid * 256 + tid) * 4;
    const float4 v = *(const float4*)(x + i);
    u16x4 r = {f2bf(v.x), f2bf(v.y), f2bf(v.z), f2bf(v.w)};
    *(u16x4*)(xb + i) = r;
    return;
  }
  __shared__ u16 tile[64][65];
  const float* w;
  u16* wt;
  int K, N, n0, k0;
  if (bid < 4864) {
    const int id = bid - 4096;  // transpose w_qkv (48 x 16 tiles)
    w = wq; wt = wqT; K = 1024; N = 3072;
    n0 = (id % 48) * 64; k0 = (id / 48) * 64;
  } else {
    const int id = bid - 4864;  // transpose w_proj (16 x 16 tiles)
    w = wp; wt = wpT; K = 1024; N = 1024;
    n0 = (id % 16) * 64; k0 = (id / 16) * 64;
  }
#pragma unroll
  for (int it = 0; it < 16; ++it) {
    const int idx = it * 256 + tid;
    const int r = idx >> 6, c = idx & 63;
    tile[r][c] = f2bf(w[(size_t)(k0 + r) * N + n0 + c]);
  }
  __syncthreads();
#pragma unroll
  for (int it = 0; it < 16; ++it) {
    const int idx = it * 256 + tid;
    const int r2 = idx >> 6, c2 = idx & 63;
    wt[(size_t)(n0 + r2) * K + k0 + c2] = tile[c2][r2];
  }
}

// ---------------- bf16 GEMM: C[M][N] = A[M][K] * Bt[N][K]^T ----------------
// m97 structure + prefetch double-buffer + XCD-chunked swizzle.
// MODE 1: f32 out (final projection). MODE 2 (BM=128): fused RoPE epilogue — whole
// 128-col tile is uniformly q, k, or v. Q/K path = R11's known-good (inline sincosf,
// scatter stores, VGPR 80). V path = LDS transpose through dead As/Bs -> coalesced u16x8.
template <int BM, int MODE>
__global__ __launch_bounds__(256) void gemm_bt(const u16* __restrict__ A, const u16* __restrict__ Bt,
                                               void* __restrict__ Cout, int M, int N, int K,
                                               u16* __restrict__ Qo, u16* __restrict__ Ko,
                                               u16* __restrict__ Vto) {
  constexpr int MR = (BM == 128) ? 4 : 2;   // m-fragments per wave
  constexpr int SMEM_U16 = BM * 64 + 8192;  // As[2]+Bs[2]; ==16384 u16 (32KB tile) when BM=128
  __shared__ __align__(16) u16 smem[SMEM_U16];
  u16* As0 = smem;
  u16* As1 = smem + BM * 32;
  u16* Bs0 = smem + BM * 64;
  u16* Bs1 = smem + BM * 64 + 4096;
  const int tid = threadIdx.x;
  const int wave = tid >> 6;
  const int lane = tid & 63;
  const int la = lane & 15, lb = lane >> 4;
  const int nwg = gridDim.x * gridDim.y;
  int lid = blockIdx.y * gridDim.x + blockIdx.x;
  lid = (lid & 7) * (nwg >> 3) + (lid >> 3);
  const int m0 = (lid % gridDim.x) * BM, n0 = (lid / gridDim.x) * 128;
  const int wr = (wave >> 1) * (BM / 2), wc = (wave & 1) * 64;
  const int srow = lane >> 2;       // 0..15
  const int scol = (lane & 3) * 8;  // 0,8,16,24
  const int c0 = wave * 2;

  auto stage = [&](int bb, int k0) {
    u16* Asb = bb ? As1 : As0;
    u16* Bsb = bb ? Bs1 : Bs0;
    if (BM == 128) {
#pragma unroll
      for (int c2 = 0; c2 < 2; ++c2) {
        const int c = c0 + c2;
        const int row = c * 16 + srow;
        gload_lds16(A + (size_t)(m0 + row) * K + k0 + scol, Asb + c * 512);
      }
    } else {
      const int row = wave * 16 + srow;
      gload_lds16(A + (size_t)(m0 + row) * K + k0 + scol, Asb + wave * 512);
    }
#pragma unroll
    for (int c2 = 0; c2 < 2; ++c2) {
      const int c = c0 + c2;
      const int row = c * 16 + srow;
      gload_lds16(Bt + (size_t)(n0 + row) * K + k0 + scol, Bsb + c * 512);
    }
  };

  f32x4 acc[MR][4] = {};
  const int nk = K >> 5;
  stage(0, 0);
  __syncthreads();
  int cur = 0;
  for (int t = 0; t < nk; ++t) {
    if (t + 1 < nk) stage(cur ^ 1, (t + 1) * 32);  // prefetch under compute
    const u16* Asc = cur ? As1 : As0;
    const u16* Bsc = cur ? Bs1 : Bs0;
    bf16x8 af[MR], bfr[4];
#pragma unroll
    for (int m = 0; m < MR; ++m) af[m] = *(const bf16x8*)&Asc[(wr + m * 16 + la) * 32 + lb * 8];
#pragma unroll
    for (int n = 0; n < 4; ++n) bfr[n] = *(const bf16x8*)&Bsc[(wc + n * 16 + la) * 32 + lb * 8];
#pragma unroll
    for (int m = 0; m < MR; ++m)
#pragma unroll
      for (int n = 0; n < 4; ++n)
        acc[m][n] = __builtin_amdgcn_mfma_f32_16x16x32_bf16(af[m], bfr[n], acc[m][n], 0, 0, 0);
    __syncthreads();  // drains prefetch vmcnt + guards buffer reuse
    cur ^= 1;
  }

  if (MODE == 2) {
    const int reg = n0 >> 10;  // 0=q 1=k 2=v -- uniform for the whole block
    if (reg == 2) {
      // ---- V: transpose through LDS (alias of dead As/Bs), coalesced u16x8 out ----
#pragma unroll
      for (int n = 0; n < 4; ++n) {
        const int cl = wc + n * 16 + la;
#pragma unroll
        for (int m = 0; m < MR; ++m)
#pragma unroll
          for (int j = 0; j < 4; ++j) {
            const int row = wr + m * 16 + lb * 4 + j;
            smem[cl * 128 + (row ^ ((cl & 7) << 3))] = f2bf(acc[m][n][j]);
          }
      }
      __syncthreads();
      const int bb = m0 >> 11;
      const int tbase = m0 & 2047;
      const int h0 = (n0 & 1023) >> 6;
#pragma unroll
      for (int it = 0; it < 8; ++it) {
        const int cl = it * 16 + (tid >> 4);
        const int tch = tid & 15;
        const u16x8 v = *(const u16x8*)&smem[cl * 128 + ((tch * 8) ^ ((cl & 7) << 3))];
        const int d = cl & 63;
        const int h = h0 + (cl >> 6);
        *(u16x8*)(Vto + ((size_t)(bb * 16 + h) * 64 + d) * 2048 + tbase + tch * 8) = v;
      }
      return;
    }
    // ---- Q/K: R11 known-good path (inline sincosf, scatter stores) ----
    const float NEG = -0.41524101186f;  // -log2(10000)/32
    const float QSC = 0.18033688011f;   // 0.125 * log2(e)
#pragma unroll
    for (int n = 0; n < 4; ++n) {
      const int c = n0 + wc + n * 16 + la;  // global qkv column
      const int d = c & 63;
      const int h = (c & 1023) >> 6;
      const float invf = exp2f(NEG * (float)(d & 31));
      const float sgn = (d & 1) ? 1.0f : -1.0f;  // rot[2i]=-x[2i+1], rot[2i+1]=x[2i]
      float s1, c1, s16, c16;
      sincosf(invf, &s1, &c1);
      sincosf(16.0f * invf, &s16, &c16);
      const int tb = m0 + wr + lb * 4;
      const int bb = tb >> 11;
      const int tlb = tb & 2047;
      const size_t plane = (size_t)(bb * 16 + h) * 2048;
      float sm, cm;
      sincosf((float)tlb * invf, &sm, &cm);
      u16* dst = (reg == 0) ? Qo : Ko;
      const float qs = (reg == 0) ? QSC : 1.0f;
#pragma unroll
      for (int m = 0; m < MR; ++m) {
        float cj = cm, sj = sm;
#pragma unroll
        for (int j = 0; j < 4; ++j) {
          const float val = acc[m][n][j];
          const float prt = __shfl_xor(val, 1);  // rotation partner (adjacent col = adjacent lane)
          const float out = (val * cj + sgn * prt * sj) * qs;
          dst[(plane + tlb + m * 16 + j) * 64 + d] = f2bf(out);
          const float cn = cj * c1 - sj * s1, sn = sj * c1 + cj * s1;  // angle += invf
          cj = cn; sj = sn;
        }
        const float cn = cm * c16 - sm * s16, sn = sm * c16 + cm * s16;  // angle += 16*invf
        cm = cn; sm = sn;
      }
    }
    return;
  }

#pragma unroll
  for (int m = 0; m < MR; ++m)
#pragma unroll
    for (int n = 0; n < 4; ++n)
#pragma unroll
      for (int j = 0; j < 4; ++j) {
        const int row = m0 + wr + m * 16 + lb * 4 + j;
        const int col = n0 + wc + n * 16 + la;
        if (MODE == 1)
          ((float*)Cout)[(size_t)row * N + col] = acc[m][n][j];
        else
          ((u16*)Cout)[(size_t)row * N + col] = f2bf(acc[m][n][j]);
      }
}

// ---------------- flash attention (causal): R10 known-good (K+V in LDS) ----------------
// 1024 blocks x 4 waves; block = bh plane + one 64-row band (4 strips). Heavy bands first.
// K/V staged to LDS (double-buffered, gload_lds w=16, XOR pre-swizzled source, K
// sigma-permuted). Swapped QK^T: lane la owns q-row q0+la; P lane-local for PV.
__global__ __launch_bounds__(256) void attn_kernel(const u16* __restrict__ Q, const u16* __restrict__ K,
                                                   const u16* __restrict__ Vt, u16* __restrict__ Y) {
  const int L = blockIdx.y * 32 + blockIdx.x;  // 0..1023
  const int xcd = L & 7, slot = L >> 3;        // linear id % 8 = XCD; 4 bh planes per XCD
  const int bh = xcd * 4 + (slot & 3);
  const int beta = 31 - (slot >> 2);           // band index 0..31, heavy first
  const int b = bh >> 4, h = bh & 15;
  const int wave = threadIdx.x >> 6, lane = threadIdx.x & 63;
  const int la = lane & 15, lb = lane >> 4;
  const int q0 = beta * 64 + wave * 16;  // this wave's 16-row strip
  const int NT = beta + 1;               // kv tiles for the whole band

  __shared__ __align__(16) u16 KV[2][2][4096];  // [buf][K/V][64x64] (swizzled; K sigma-permuted)

  const size_t plane = (size_t)bh * (2048 * 64);
  const char* Kb = (const char*)(K + plane);
  const char* Vb = (const char*)(Vt + plane);

  auto stage = [&](int buf, int kt) {
#pragma unroll
    for (int it = 0; it < 2; ++it) {
      const int ci = it * 256 + wave * 64 + lane;          // 16B chunk id 0..511
      const int row = ci >> 3;                             // LDS tile row 0..63
      const int cbs = ((ci & 7) * 16) ^ ((row & 7) << 4);  // pre-swizzled source col byte
      const int n2 = row >> 4, rho = row & 15;
      const int srow = ((n2 & 1) << 5) + ((rho >> 2) << 3) + ((n2 >> 1) << 2) + (rho & 3);
      gload_lds16(Kb + (size_t)(kt * 64 + srow) * 128 + cbs,
                  (char*)&KV[buf][0][0] + it * 4096 + wave * 1024);
      gload_lds16(Vb + (size_t)row * 4096 + (size_t)kt * 128 + cbs,
                  (char*)&KV[buf][1][0] + it * 4096 + wave * 1024);
    }
  };

  stage(0, 0);

  bf16x8 qf[2];
#pragma unroll
  for (int s = 0; s < 2; ++s)
    qf[s] = *(const bf16x8*)(Q + plane + (size_t)(q0 + la) * 64 + s * 32 + lb * 8);

  f32x4 o[4] = {};
  float mreg = -1.0e30f;
  float plr = 0.f;

  // deswizzled u16 column index within a row, per s (32-col sub-block)
  const int x0 = (la & 7) << 4;
  const int cu0 = ((lb * 16) ^ x0) >> 1;
  const int cu1 = ((64 + lb * 16) ^ x0) >> 1;

  __syncthreads();
  int buf = 0;
  for (int kt = 0; kt < NT; ++kt) {
    if (kt + 1 < NT) stage(buf ^ 1, kt + 1);
    const u16* Kc = KV[buf][0];
    const u16* Vc = KV[buf][1];

    bf16x8 kf[2][4];
#pragma unroll
    for (int n = 0; n < 4; ++n) {
      kf[0][n] = *(const bf16x8*)&Kc[(n * 16 + la) * 64 + cu0];
      kf[1][n] = *(const bf16x8*)&Kc[(n * 16 + la) * 64 + cu1];
    }

    // ---- swapped QK^T ----
    const int rowq = q0 + la;  // this lane's q-row
    f32x4 sa[4] = {};
    __builtin_amdgcn_s_setprio(1);
#pragma unroll
    for (int s = 0; s < 2; ++s)
#pragma unroll
      for (int n = 0; n < 4; ++n)
        sa[n] = __builtin_amdgcn_mfma_f32_16x16x32_bf16(kf[s][n], qf[s], sa[n], 0, 0, 0);
    __builtin_amdgcn_s_setprio(0);
    // lane holds S[rowq][kt*64 + sig(n, lb*4+j)], sig = (n&1)*32 + lb*8 + (n>>1)*4 + j
    if (kt == NT - 1) {  // diagonal tile: causal mask
#pragma unroll
      for (int n = 0; n < 4; ++n)
#pragma unroll
        for (int j = 0; j < 4; ++j) {
          const int col = kt * 64 + ((n & 1) << 5) + (lb << 3) + ((n >> 1) << 2) + j;
          if (col > rowq) sa[n][j] = -1.0e30f;
        }
    }
    // ---- per-lane softmax (defer-max) ----
    float mn_[4];
#pragma unroll
    for (int n = 0; n < 4; ++n)
      mn_[n] = fmaxf(fmaxf(sa[n][0], sa[n][1]), fmaxf(sa[n][2], sa[n][3]));
    const float lmax = fmaxf(fmaxf(mn_[0], mn_[1]), fmaxf(mn_[2], mn_[3]));
    if (__any(lmax > mreg + 8.0f)) {
      float v = fmaxf(lmax, __shfl_xor(lmax, 16));
      v = fmaxf(v, __shfl_xor(v, 32));
      const float mn = fmaxf(mreg, v);
      const float al = __builtin_amdgcn_exp2f(mreg - mn);
      plr *= al;
      mreg = mn;
      float alj[4];
#pragma unroll
      for (int j = 0; j < 4; ++j) alj[j] = __shfl(al, lb * 4 + j);
#pragma unroll
      for (int n = 0; n < 4; ++n)
#pragma unroll
        for (int j = 0; j < 4; ++j) o[n][j] *= alj[j];
    }
    u32 w[4][2];
    float ps = 0.f;
#pragma unroll
    for (int n = 0; n < 4; ++n) {
      const float p0 = __builtin_amdgcn_exp2f(sa[n][0] - mreg);
      const float p1 = __builtin_amdgcn_exp2f(sa[n][1] - mreg);
      const float p2 = __builtin_amdgcn_exp2f(sa[n][2] - mreg);
      const float p3 = __builtin_amdgcn_exp2f(sa[n][3] - mreg);
      ps += (p0 + p1) + (p2 + p3);
      w[n][0] = (u32)f2bf(p0) | ((u32)f2bf(p1) << 16);
      w[n][1] = (u32)f2bf(p2) | ((u32)f2bf(p3) << 16);
    }
    plr += ps;
    bf16x8 paf[2];
    paf[0] = __builtin_bit_cast(bf16x8, (u32x4){w[0][0], w[0][1], w[2][0], w[2][1]});
    paf[1] = __builtin_bit_cast(bf16x8, (u32x4){w[1][0], w[1][1], w[3][0], w[3][1]});

    // ---- PV (P lane-local in A-fragment layout) ----
    bf16x8 vf[2][4];
#pragma unroll
    for (int n = 0; n < 4; ++n) {
      vf[0][n] = *(const bf16x8*)&Vc[(n * 16 + la) * 64 + cu0];
      vf[1][n] = *(const bf16x8*)&Vc[(n * 16 + la) * 64 + cu1];
    }
    __builtin_amdgcn_s_setprio(1);
#pragma unroll
    for (int n = 0; n < 4; ++n)
#pragma unroll
      for (int s = 0; s < 2; ++s)
        o[n] = __builtin_amdgcn_mfma_f32_16x16x32_bf16(paf[s], vf[s][n], o[n], 0, 0, 0);
    __builtin_amdgcn_s_setprio(0);

    __syncthreads();
    buf ^= 1;
  }

  // ---- epilogue: 2-step row-sum reduce, shfl rinv to o-rows, write ----
  float ls = plr;
  ls += __shfl_xor(ls, 16);
  ls += __shfl_xor(ls, 32);
  const float rinv = __builtin_amdgcn_rcpf(ls);
  float rj[4];
#pragma unroll
  for (int j = 0; j < 4; ++j) rj[j] = __shfl(rinv, lb * 4 + j);
#pragma unroll
  for (int n = 0; n < 4; ++n)
#pragma unroll
    for (int j = 0; j < 4; ++j) {
      const int t = q0 + lb * 4 + j;
      const int c = h * 64 + n * 16 + la;
      Y[((size_t)b * 2048 + t) * 1024 + c] = f2bf(o[n][j] * rj[j]);
    }
}

extern "C" void kernel_launch(void* const* d_in, const int* in_sizes, int n_in, void* d_out,
                              int out_size, void* d_ws, size_t ws_size, hipStream_t stream) {
  (void)in_sizes; (void)n_in; (void)out_size; (void)ws_size;
  const float* x = (const float*)d_in[0];
  const float* w_qkv = (const float*)d_in[1];
  const float* w_proj = (const float*)d_in[2];
  char* ws = (char*)d_ws;
  // workspace layout (bytes), total 40 MiB
  u16* xb     = (u16*)(ws);             // 4096*1024 bf16  (8 MiB)  -- reused as y later
  u16* wqkvT  = (u16*)(ws + 8388608);   // 3072*1024       (6 MiB)
  u16* wprojT = (u16*)(ws + 14680064);  // 1024*1024       (2 MiB)
  u16* q      = (u16*)(ws + 16777216);  // 32*2048*64      (8 MiB)
  u16* k      = (u16*)(ws + 25165824);  // 32*2048*64      (8 MiB)
  u16* vt     = (u16*)(ws + 33554432);  // 32*64*2048      (8 MiB)
  u16* y      = xb;                     // alias: xb dead after GEMM1

  prep_kernel<<<dim3(5120), dim3(256), 0, stream>>>(x, xb, w_qkv, wqkvT, w_proj, wprojT);
  gemm_bt<128, 2><<<dim3(32, 24), dim3(256), 0, stream>>>(xb, wqkvT, nullptr, 4096, 3072, 1024,
                                                          q, k, vt);
  attn_kernel<<<dim3(32, 32), dim3(256), 0, stream>>>(q, k, vt, y);
  gemm_bt<64, 1><<<dim3(64, 8), dim3(256), 0, stream>>>(y, wprojT, d_out, 4096, 1024, 1024,
                                                        nullptr, nullptr, nullptr);
}

// Round 16
// 106.275 us; speedup vs baseline: 1.0751x; 1.0751x over previous
//
#include <hip/hip_runtime.h>
#include <hip/hip_bf16.h>

typedef unsigned short u16;
typedef unsigned int u32;
typedef __attribute__((ext_vector_type(8))) __bf16 bf16x8;
typedef __attribute__((ext_vector_type(4))) float f32x4;
typedef __attribute__((ext_vector_type(4))) u16 u16x4;
typedef __attribute__((ext_vector_type(4))) u32 u32x4;

__device__ __forceinline__ u16 f2bf(float f) {
  return __builtin_bit_cast(u16, (__bf16)f);  // native RNE cvt
}

__device__ __forceinline__ void gload_lds16(const void* g, void* l) {
  __builtin_amdgcn_global_load_lds((const __attribute__((address_space(1))) void*)g,
                                   (__attribute__((address_space(3))) void*)l, 16, 0, 0);
}

// ---------------- fused prep: fp32->bf16 cvt of x + both weight transposes ----------------
__global__ __launch_bounds__(256) void prep_kernel(const float* __restrict__ x, u16* __restrict__ xb,
                                                   const float* __restrict__ wq, u16* __restrict__ wqT,
                                                   const float* __restrict__ wp, u16* __restrict__ wpT) {
  const int bid = blockIdx.x;
  const int tid = threadIdx.x;
  if (bid < 4096) {  // cvt x
    const int i = (bid * 256 + tid) * 4;
    const float4 v = *(const float4*)(x + i);
    u16x4 r = {f2bf(v.x), f2bf(v.y), f2bf(v.z), f2bf(v.w)};
    *(u16x4*)(xb + i) = r;
    return;
  }
  __shared__ u16 tile[64][65];
  const float* w;
  u16* wt;
  int K, N, n0, k0;
  if (bid < 4864) {
    const int id = bid - 4096;  // transpose w_qkv (48 x 16 tiles)
    w = wq; wt = wqT; K = 1024; N = 3072;
    n0 = (id % 48) * 64; k0 = (id / 48) * 64;
  } else {
    const int id = bid - 4864;  // transpose w_proj (16 x 16 tiles)
    w = wp; wt = wpT; K = 1024; N = 1024;
    n0 = (id % 16) * 64; k0 = (id / 16) * 64;
  }
#pragma unroll
  for (int it = 0; it < 16; ++it) {
    const int idx = it * 256 + tid;
    const int r = idx >> 6, c = idx & 63;
    tile[r][c] = f2bf(w[(size_t)(k0 + r) * N + n0 + c]);
  }
  __syncthreads();
#pragma unroll
  for (int it = 0; it < 16; ++it) {
    const int idx = it * 256 + tid;
    const int r2 = idx >> 6, c2 = idx & 63;
    wt[(size_t)(n0 + r2) * K + k0 + c2] = tile[c2][r2];
  }
}

// ---------------- bf16 GEMM: C[M][N] = A[M][K] * Bt[N][K]^T ----------------
// m97 structure + prefetch double-buffer + XCD-chunked swizzle.
// MODE 1: f32 out (final projection). MODE 2 (BM=128 only): fused RoPE epilogue —
// q/k tiles rotated via lane-pair shfl + angle recurrence, v tiles transposed to Vt.
// NOTE (R13-R15 lesson): keep this epilogue exactly as-is. Trig-hoisting and LDS-transpose
// variants raise VGPR 80->92..116, drop residency 5->4 blocks/CU, double FETCH. This
// config (VGPR 80, 5 blocks/CU, FETCH ~36MB) is the measured local optimum (43.6 us).
template <int BM, int MODE>
__global__ __launch_bounds__(256) void gemm_bt(const u16* __restrict__ A, const u16* __restrict__ Bt,
                                               void* __restrict__ Cout, int M, int N, int K,
                                               u16* __restrict__ Qo, u16* __restrict__ Ko,
                                               u16* __restrict__ Vto) {
  constexpr int MR = (BM == 128) ? 4 : 2;  // m-fragments per wave
  __shared__ u16 As[2][BM * 32];
  __shared__ u16 Bs[2][128 * 32];
  const int tid = threadIdx.x;
  const int wave = tid >> 6;
  const int lane = tid & 63;
  const int la = lane & 15, lb = lane >> 4;
  const int nwg = gridDim.x * gridDim.y;
  int lid = blockIdx.y * gridDim.x + blockIdx.x;
  lid = (lid & 7) * (nwg >> 3) + (lid >> 3);
  const int m0 = (lid % gridDim.x) * BM, n0 = (lid / gridDim.x) * 128;
  const int wr = (wave >> 1) * (BM / 2), wc = (wave & 1) * 64;
  const int srow = lane >> 2;       // 0..15
  const int scol = (lane & 3) * 8;  // 0,8,16,24
  const int c0 = wave * 2;

  auto stage = [&](int bb, int k0) {
    if (BM == 128) {
#pragma unroll
      for (int c2 = 0; c2 < 2; ++c2) {
        const int c = c0 + c2;
        const int row = c * 16 + srow;
        gload_lds16(A + (size_t)(m0 + row) * K + k0 + scol, As[bb] + c * 512);
      }
    } else {
      const int row = wave * 16 + srow;
      gload_lds16(A + (size_t)(m0 + row) * K + k0 + scol, As[bb] + wave * 512);
    }
#pragma unroll
    for (int c2 = 0; c2 < 2; ++c2) {
      const int c = c0 + c2;
      const int row = c * 16 + srow;
      gload_lds16(Bt + (size_t)(n0 + row) * K + k0 + scol, Bs[bb] + c * 512);
    }
  };

  f32x4 acc[MR][4] = {};
  const int nk = K >> 5;
  stage(0, 0);
  __syncthreads();
  int cur = 0;
  for (int t = 0; t < nk; ++t) {
    if (t + 1 < nk) stage(cur ^ 1, (t + 1) * 32);  // prefetch under compute
    bf16x8 af[MR], bfr[4];
#pragma unroll
    for (int m = 0; m < MR; ++m) af[m] = *(const bf16x8*)&As[cur][(wr + m * 16 + la) * 32 + lb * 8];
#pragma unroll
    for (int n = 0; n < 4; ++n) bfr[n] = *(const bf16x8*)&Bs[cur][(wc + n * 16 + la) * 32 + lb * 8];
#pragma unroll
    for (int m = 0; m < MR; ++m)
#pragma unroll
      for (int n = 0; n < 4; ++n)
        acc[m][n] = __builtin_amdgcn_mfma_f32_16x16x32_bf16(af[m], bfr[n], acc[m][n], 0, 0, 0);
    __syncthreads();  // drains prefetch vmcnt + guards buffer reuse
    cur ^= 1;
  }

  if (MODE == 2) {
    // Fused RoPE + reshape + V-transpose epilogue.
    const float NEG = -0.41524101186f;  // -log2(10000)/32
    const float QSC = 0.18033688011f;   // 0.125 * log2(e)
#pragma unroll
    for (int n = 0; n < 4; ++n) {
      const int c = n0 + wc + n * 16 + la;  // global qkv column
      const int d = c & 63;
      const int h = (c & 1023) >> 6;
      const int reg = c >> 10;  // 0=q 1=k 2=v (uniform across lanes: 16-col fragment)
      if (reg == 2) {
#pragma unroll
        for (int m = 0; m < MR; ++m) {
          const int t0 = m0 + wr + m * 16 + lb * 4;
          const int bb = t0 >> 11, tl0 = t0 & 2047;
          u16x4 pv;
#pragma unroll
          for (int j = 0; j < 4; ++j) pv[j] = f2bf(acc[m][n][j]);
          *(u16x4*)(Vto + ((size_t)(bb * 16 + h) * 64 + d) * 2048 + tl0) = pv;
        }
      } else {
        const float invf = exp2f(NEG * (float)(d & 31));
        const float sgn = (d & 1) ? 1.0f : -1.0f;  // rot[2i]=-x[2i+1], rot[2i+1]=x[2i]
        float s1, c1, s16, c16;
        sincosf(invf, &s1, &c1);
        sincosf(16.0f * invf, &s16, &c16);
        const int tb = m0 + wr + lb * 4;  // row range within one 2048-block
        const int bb = tb >> 11;
        const int tlb = tb & 2047;
        const size_t plane = (size_t)(bb * 16 + h) * 2048;
        float sm, cm;
        sincosf((float)tlb * invf, &sm, &cm);
        u16* dst = (reg == 0) ? Qo : Ko;
        const float qs = (reg == 0) ? QSC : 1.0f;
#pragma unroll
        for (int m = 0; m < MR; ++m) {
          float cj = cm, sj = sm;
#pragma unroll
          for (int j = 0; j < 4; ++j) {
            const float val = acc[m][n][j];
            const float prt = __shfl_xor(val, 1);  // pair partner (adjacent col = adjacent lane)
            const float out = (val * cj + sgn * prt * sj) * qs;
            dst[(plane + tlb + m * 16 + j) * 64 + d] = f2bf(out);
            const float cn = cj * c1 - sj * s1, sn = sj * c1 + cj * s1;  // angle += invf
            cj = cn; sj = sn;
          }
          const float cn = cm * c16 - sm * s16, sn = sm * c16 + cm * s16;  // angle += 16*invf
          cm = cn; sm = sn;
        }
      }
    }
    return;
  }

#pragma unroll
  for (int m = 0; m < MR; ++m)
#pragma unroll
    for (int n = 0; n < 4; ++n)
#pragma unroll
      for (int j = 0; j < 4; ++j) {
        const int row = m0 + wr + m * 16 + lb * 4 + j;
        const int col = n0 + wc + n * 16 + la;
        if (MODE == 1)
          ((float*)Cout)[(size_t)row * N + col] = acc[m][n][j];
        else
          ((u16*)Cout)[(size_t)row * N + col] = f2bf(acc[m][n][j]);
      }
}

// ---------------- flash attention (causal): R10 known-good (K+V in LDS) ----------------
// 1024 blocks x 4 waves; block = bh plane + one 64-row band (4 strips). Heavy bands first.
// K/V staged to LDS (double-buffered, gload_lds w=16, XOR pre-swizzled source, K
// sigma-permuted). Swapped QK^T: lane la owns q-row q0+la; P lane-local for PV.
__global__ __launch_bounds__(256) void attn_kernel(const u16* __restrict__ Q, const u16* __restrict__ K,
                                                   const u16* __restrict__ Vt, u16* __restrict__ Y) {
  const int L = blockIdx.y * 32 + blockIdx.x;  // 0..1023
  const int xcd = L & 7, slot = L >> 3;        // linear id % 8 = XCD; 4 bh planes per XCD
  const int bh = xcd * 4 + (slot & 3);
  const int beta = 31 - (slot >> 2);           // band index 0..31, heavy first
  const int b = bh >> 4, h = bh & 15;
  const int wave = threadIdx.x >> 6, lane = threadIdx.x & 63;
  const int la = lane & 15, lb = lane >> 4;
  const int q0 = beta * 64 + wave * 16;  // this wave's 16-row strip
  const int NT = beta + 1;               // kv tiles for the whole band

  __shared__ __align__(16) u16 KV[2][2][4096];  // [buf][K/V][64x64] (swizzled; K sigma-permuted)

  const size_t plane = (size_t)bh * (2048 * 64);
  const char* Kb = (const char*)(K + plane);
  const char* Vb = (const char*)(Vt + plane);

  auto stage = [&](int buf, int kt) {
#pragma unroll
    for (int it = 0; it < 2; ++it) {
      const int ci = it * 256 + wave * 64 + lane;          // 16B chunk id 0..511
      const int row = ci >> 3;                             // LDS tile row 0..63
      const int cbs = ((ci & 7) * 16) ^ ((row & 7) << 4);  // pre-swizzled source col byte
      const int n2 = row >> 4, rho = row & 15;
      const int srow = ((n2 & 1) << 5) + ((rho >> 2) << 3) + ((n2 >> 1) << 2) + (rho & 3);
      gload_lds16(Kb + (size_t)(kt * 64 + srow) * 128 + cbs,
                  (char*)&KV[buf][0][0] + it * 4096 + wave * 1024);
      gload_lds16(Vb + (size_t)row * 4096 + (size_t)kt * 128 + cbs,
                  (char*)&KV[buf][1][0] + it * 4096 + wave * 1024);
    }
  };

  stage(0, 0);

  bf16x8 qf[2];
#pragma unroll
  for (int s = 0; s < 2; ++s)
    qf[s] = *(const bf16x8*)(Q + plane + (size_t)(q0 + la) * 64 + s * 32 + lb * 8);

  f32x4 o[4] = {};
  float mreg = -1.0e30f;
  float plr = 0.f;

  // deswizzled u16 column index within a row, per s (32-col sub-block)
  const int x0 = (la & 7) << 4;
  const int cu0 = ((lb * 16) ^ x0) >> 1;
  const int cu1 = ((64 + lb * 16) ^ x0) >> 1;

  __syncthreads();
  int buf = 0;
  for (int kt = 0; kt < NT; ++kt) {
    if (kt + 1 < NT) stage(buf ^ 1, kt + 1);
    const u16* Kc = KV[buf][0];
    const u16* Vc = KV[buf][1];

    bf16x8 kf[2][4];
#pragma unroll
    for (int n = 0; n < 4; ++n) {
      kf[0][n] = *(const bf16x8*)&Kc[(n * 16 + la) * 64 + cu0];
      kf[1][n] = *(const bf16x8*)&Kc[(n * 16 + la) * 64 + cu1];
    }

    // ---- swapped QK^T ----
    const int rowq = q0 + la;  // this lane's q-row
    f32x4 sa[4] = {};
    __builtin_amdgcn_s_setprio(1);
#pragma unroll
    for (int s = 0; s < 2; ++s)
#pragma unroll
      for (int n = 0; n < 4; ++n)
        sa[n] = __builtin_amdgcn_mfma_f32_16x16x32_bf16(kf[s][n], qf[s], sa[n], 0, 0, 0);
    __builtin_amdgcn_s_setprio(0);
    // lane holds S[rowq][kt*64 + sig(n, lb*4+j)], sig = (n&1)*32 + lb*8 + (n>>1)*4 + j
    if (kt == NT - 1) {  // diagonal tile: causal mask
#pragma unroll
      for (int n = 0; n < 4; ++n)
#pragma unroll
        for (int j = 0; j < 4; ++j) {
          const int col = kt * 64 + ((n & 1) << 5) + (lb << 3) + ((n >> 1) << 2) + j;
          if (col > rowq) sa[n][j] = -1.0e30f;
        }
    }
    // ---- per-lane softmax (defer-max) ----
    float mn_[4];
#pragma unroll
    for (int n = 0; n < 4; ++n)
      mn_[n] = fmaxf(fmaxf(sa[n][0], sa[n][1]), fmaxf(sa[n][2], sa[n][3]));
    const float lmax = fmaxf(fmaxf(mn_[0], mn_[1]), fmaxf(mn_[2], mn_[3]));
    if (__any(lmax > mreg + 8.0f)) {
      float v = fmaxf(lmax, __shfl_xor(lmax, 16));
      v = fmaxf(v, __shfl_xor(v, 32));
      const float mn = fmaxf(mreg, v);
      const float al = __builtin_amdgcn_exp2f(mreg - mn);
      plr *= al;
      mreg = mn;
      float alj[4];
#pragma unroll
      for (int j = 0; j < 4; ++j) alj[j] = __shfl(al, lb * 4 + j);
#pragma unroll
      for (int n = 0; n < 4; ++n)
#pragma unroll
        for (int j = 0; j < 4; ++j) o[n][j] *= alj[j];
    }
    u32 w[4][2];
    float ps = 0.f;
#pragma unroll
    for (int n = 0; n < 4; ++n) {
      const float p0 = __builtin_amdgcn_exp2f(sa[n][0] - mreg);
      const float p1 = __builtin_amdgcn_exp2f(sa[n][1] - mreg);
      const float p2 = __builtin_amdgcn_exp2f(sa[n][2] - mreg);
      const float p3 = __builtin_amdgcn_exp2f(sa[n][3] - mreg);
      ps += (p0 + p1) + (p2 + p3);
      w[n][0] = (u32)f2bf(p0) | ((u32)f2bf(p1) << 16);
      w[n][1] = (u32)f2bf(p2) | ((u32)f2bf(p3) << 16);
    }
    plr += ps;
    bf16x8 paf[2];
    paf[0] = __builtin_bit_cast(bf16x8, (u32x4){w[0][0], w[0][1], w[2][0], w[2][1]});
    paf[1] = __builtin_bit_cast(bf16x8, (u32x4){w[1][0], w[1][1], w[3][0], w[3][1]});

    // ---- PV (P lane-local in A-fragment layout) ----
    bf16x8 vf[2][4];
#pragma unroll
    for (int n = 0; n < 4; ++n) {
      vf[0][n] = *(const bf16x8*)&Vc[(n * 16 + la) * 64 + cu0];
      vf[1][n] = *(const bf16x8*)&Vc[(n * 16 + la) * 64 + cu1];
    }
    __builtin_amdgcn_s_setprio(1);
#pragma unroll
    for (int n = 0; n < 4; ++n)
#pragma unroll
      for (int s = 0; s < 2; ++s)
        o[n] = __builtin_amdgcn_mfma_f32_16x16x32_bf16(paf[s], vf[s][n], o[n], 0, 0, 0);
    __builtin_amdgcn_s_setprio(0);

    __syncthreads();
    buf ^= 1;
  }

  // ---- epilogue: 2-step row-sum reduce, shfl rinv to o-rows, write ----
  float ls = plr;
  ls += __shfl_xor(ls, 16);
  ls += __shfl_xor(ls, 32);
  const float rinv = __builtin_amdgcn_rcpf(ls);
  float rj[4];
#pragma unroll
  for (int j = 0; j < 4; ++j) rj[j] = __shfl(rinv, lb * 4 + j);
#pragma unroll
  for (int n = 0; n < 4; ++n)
#pragma unroll
    for (int j = 0; j < 4; ++j) {
      const int t = q0 + lb * 4 + j;
      const int c = h * 64 + n * 16 + la;
      Y[((size_t)b * 2048 + t) * 1024 + c] = f2bf(o[n][j] * rj[j]);
    }
}

extern "C" void kernel_launch(void* const* d_in, const int* in_sizes, int n_in, void* d_out,
                              int out_size, void* d_ws, size_t ws_size, hipStream_t stream) {
  (void)in_sizes; (void)n_in; (void)out_size; (void)ws_size;
  const float* x = (const float*)d_in[0];
  const float* w_qkv = (const float*)d_in[1];
  const float* w_proj = (const float*)d_in[2];
  char* ws = (char*)d_ws;
  // workspace layout (bytes), total 40 MiB
  u16* xb     = (u16*)(ws);             // 4096*1024 bf16  (8 MiB)  -- reused as y later
  u16* wqkvT  = (u16*)(ws + 8388608);   // 3072*1024       (6 MiB)
  u16* wprojT = (u16*)(ws + 14680064);  // 1024*1024       (2 MiB)
  u16* q      = (u16*)(ws + 16777216);  // 32*2048*64      (8 MiB)
  u16* k      = (u16*)(ws + 25165824);  // 32*2048*64      (8 MiB)
  u16* vt     = (u16*)(ws + 33554432);  // 32*64*2048      (8 MiB)
  u16* y      = xb;                     // alias: xb dead after GEMM1

  prep_kernel<<<dim3(5120), dim3(256), 0, stream>>>(x, xb, w_qkv, wqkvT, w_proj, wprojT);
  gemm_bt<128, 2><<<dim3(32, 24), dim3(256), 0, stream>>>(xb, wqkvT, nullptr, 4096, 3072, 1024,
                                                          q, k, vt);
  attn_kernel<<<dim3(32, 32), dim3(256), 0, stream>>>(q, k, vt, y);
  gemm_bt<64, 1><<<dim3(64, 8), dim3(256), 0, stream>>>(y, wprojT, d_out, 4096, 1024, 1024,
                                                        nullptr, nullptr, nullptr);
}

// Round 17
// 104.032 us; speedup vs baseline: 1.0983x; 1.0216x over previous
//
#include <hip/hip_runtime.h>
#include <hip/hip_bf16.h>

typedef unsigned short u16;
typedef unsigned int u32;
typedef __attribute__((ext_vector_type(8))) __bf16 bf16x8;
typedef __attribute__((ext_vector_type(4))) float f32x4;
typedef __attribute__((ext_vector_type(4))) u16 u16x4;
typedef __attribute__((ext_vector_type(4))) u32 u32x4;

__device__ __forceinline__ u16 f2bf(float f) {
  return __builtin_bit_cast(u16, (__bf16)f);  // native RNE cvt
}

__device__ __forceinline__ void gload_lds16(const void* g, void* l) {
  __builtin_amdgcn_global_load_lds((const __attribute__((address_space(1))) void*)g,
                                   (__attribute__((address_space(3))) void*)l, 16, 0, 0);
}

// ---------------- fused prep: fp32->bf16 cvt of x + both weight transposes ----------------
__global__ __launch_bounds__(256) void prep_kernel(const float* __restrict__ x, u16* __restrict__ xb,
                                                   const float* __restrict__ wq, u16* __restrict__ wqT,
                                                   const float* __restrict__ wp, u16* __restrict__ wpT) {
  const int bid = blockIdx.x;
  const int tid = threadIdx.x;
  if (bid < 4096) {  // cvt x
    const int i = (bid * 256 + tid) * 4;
    const float4 v = *(const float4*)(x + i);
    u16x4 r = {f2bf(v.x), f2bf(v.y), f2bf(v.z), f2bf(v.w)};
    *(u16x4*)(xb + i) = r;
    return;
  }
  __shared__ u16 tile[64][65];
  const float* w;
  u16* wt;
  int K, N, n0, k0;
  if (bid < 4864) {
    const int id = bid - 4096;  // transpose w_qkv (48 x 16 tiles)
    w = wq; wt = wqT; K = 1024; N = 3072;
    n0 = (id % 48) * 64; k0 = (id / 48) * 64;
  } else {
    const int id = bid - 4864;  // transpose w_proj (16 x 16 tiles)
    w = wp; wt = wpT; K = 1024; N = 1024;
    n0 = (id % 16) * 64; k0 = (id / 16) * 64;
  }
#pragma unroll
  for (int it = 0; it < 16; ++it) {
    const int idx = it * 256 + tid;
    const int r = idx >> 6, c = idx & 63;
    tile[r][c] = f2bf(w[(size_t)(k0 + r) * N + n0 + c]);
  }
  __syncthreads();
#pragma unroll
  for (int it = 0; it < 16; ++it) {
    const int idx = it * 256 + tid;
    const int r2 = idx >> 6, c2 = idx & 63;
    wt[(size_t)(n0 + r2) * K + k0 + c2] = tile[c2][r2];
  }
}

// ---------------- bf16 GEMM: C[M][N] = A[M][K] * Bt[N][K]^T ----------------
// m97 structure + prefetch double-buffer + XCD-chunked swizzle.
// MODE 1: f32 out (final projection). MODE 2 (BM=128 only): fused RoPE epilogue.
// R16 change: Q/K epilogue is n-INNERMOST so the 4 n-stores complete one full 128B
// line per (m,j,lb-row) back-to-back (kills partial-line write amplification).
// Trig = two parity recurrences (6 sincosf + 2 exp2f, ~16 live floats). V path and
// everything else byte-identical to the R12/R16 known-good (VGPR-80 / 5-blocks-CU cliff).
template <int BM, int MODE>
__global__ __launch_bounds__(256) void gemm_bt(const u16* __restrict__ A, const u16* __restrict__ Bt,
                                               void* __restrict__ Cout, int M, int N, int K,
                                               u16* __restrict__ Qo, u16* __restrict__ Ko,
                                               u16* __restrict__ Vto) {
  constexpr int MR = (BM == 128) ? 4 : 2;  // m-fragments per wave
  __shared__ u16 As[2][BM * 32];
  __shared__ u16 Bs[2][128 * 32];
  const int tid = threadIdx.x;
  const int wave = tid >> 6;
  const int lane = tid & 63;
  const int la = lane & 15, lb = lane >> 4;
  const int nwg = gridDim.x * gridDim.y;
  int lid = blockIdx.y * gridDim.x + blockIdx.x;
  lid = (lid & 7) * (nwg >> 3) + (lid >> 3);
  const int m0 = (lid % gridDim.x) * BM, n0 = (lid / gridDim.x) * 128;
  const int wr = (wave >> 1) * (BM / 2), wc = (wave & 1) * 64;
  const int srow = lane >> 2;       // 0..15
  const int scol = (lane & 3) * 8;  // 0,8,16,24
  const int c0 = wave * 2;

  auto stage = [&](int bb, int k0) {
    if (BM == 128) {
#pragma unroll
      for (int c2 = 0; c2 < 2; ++c2) {
        const int c = c0 + c2;
        const int row = c * 16 + srow;
        gload_lds16(A + (size_t)(m0 + row) * K + k0 + scol, As[bb] + c * 512);
      }
    } else {
      const int row = wave * 16 + srow;
      gload_lds16(A + (size_t)(m0 + row) * K + k0 + scol, As[bb] + wave * 512);
    }
#pragma unroll
    for (int c2 = 0; c2 < 2; ++c2) {
      const int c = c0 + c2;
      const int row = c * 16 + srow;
      gload_lds16(Bt + (size_t)(n0 + row) * K + k0 + scol, Bs[bb] + c * 512);
    }
  };

  f32x4 acc[MR][4] = {};
  const int nk = K >> 5;
  stage(0, 0);
  __syncthreads();
  int cur = 0;
  for (int t = 0; t < nk; ++t) {
    if (t + 1 < nk) stage(cur ^ 1, (t + 1) * 32);  // prefetch under compute
    bf16x8 af[MR], bfr[4];
#pragma unroll
    for (int m = 0; m < MR; ++m) af[m] = *(const bf16x8*)&As[cur][(wr + m * 16 + la) * 32 + lb * 8];
#pragma unroll
    for (int n = 0; n < 4; ++n) bfr[n] = *(const bf16x8*)&Bs[cur][(wc + n * 16 + la) * 32 + lb * 8];
#pragma unroll
    for (int m = 0; m < MR; ++m)
#pragma unroll
      for (int n = 0; n < 4; ++n)
        acc[m][n] = __builtin_amdgcn_mfma_f32_16x16x32_bf16(af[m], bfr[n], acc[m][n], 0, 0, 0);
    __syncthreads();  // drains prefetch vmcnt + guards buffer reuse
    cur ^= 1;
  }

  if (MODE == 2) {
    // Fused RoPE + reshape + V-transpose epilogue.
    const float NEG = -0.41524101186f;  // -log2(10000)/32
    const float QSC = 0.18033688011f;   // 0.125 * log2(e)
    const int reg = n0 >> 10;           // 0=q 1=k 2=v (uniform for the whole 128-col block)
    if (reg == 2) {
      // ---- V: direct u16x4 scatter (lines completed per (n, m-set) — measured OK) ----
#pragma unroll
      for (int n = 0; n < 4; ++n) {
        const int c = n0 + wc + n * 16 + la;
        const int d = c & 63;
        const int h = (c & 1023) >> 6;
#pragma unroll
        for (int m = 0; m < MR; ++m) {
          const int t0 = m0 + wr + m * 16 + lb * 4;
          const int bb = t0 >> 11, tl0 = t0 & 2047;
          u16x4 pv;
#pragma unroll
          for (int j = 0; j < 4; ++j) pv[j] = f2bf(acc[m][n][j]);
          *(u16x4*)(Vto + ((size_t)(bb * 16 + h) * 64 + d) * 2048 + tl0) = pv;
        }
      }
      return;
    }
    // ---- Q/K: RoPE, n-innermost store order (full-line write combining) ----
    // d(n) = n*16+la (wc&63==0); d&31 = (n&1)*16 + la -> two invf parities.
    u16* dst = (reg == 0) ? Qo : Ko;
    const float qs = (reg == 0) ? QSC : 1.0f;
    const float sgn = (la & 1) ? 1.0f : -1.0f;  // rot[2i]=-x[2i+1], rot[2i+1]=x[2i]
    const int h = ((n0 & 1023) >> 6) + (wc >> 6);  // per-wave constant head
    const int tb = m0 + wr + lb * 4;
    const int bb = tb >> 11;
    const int tlb = tb & 2047;
    const size_t plane = (size_t)(bb * 16 + h) * 2048;
    const float invf0 = exp2f(NEG * (float)la);
    const float invf1 = exp2f(NEG * (float)(16 + la));
    float s1_0, c1_0, s1_1, c1_1, s16_0, c16_0, s16_1, c16_1, sm0, cm0, sm1, cm1;
    sincosf(invf0, &s1_0, &c1_0);
    sincosf(invf1, &s1_1, &c1_1);
    sincosf(16.0f * invf0, &s16_0, &c16_0);
    sincosf(16.0f * invf1, &s16_1, &c16_1);
    sincosf((float)tlb * invf0, &sm0, &cm0);
    sincosf((float)tlb * invf1, &sm1, &cm1);
#pragma unroll
    for (int m = 0; m < MR; ++m) {
      float cj0 = cm0, sj0 = sm0, cj1 = cm1, sj1 = sm1;
#pragma unroll
      for (int j = 0; j < 4; ++j) {
        const size_t rowoff = (plane + tlb + m * 16 + j) * 64;
#pragma unroll
        for (int n = 0; n < 4; ++n) {
          const float val = acc[m][n][j];
          const float prt = __shfl_xor(val, 1);  // rotation partner (adjacent col = adjacent lane)
          const float c = (n & 1) ? cj1 : cj0;
          const float s = (n & 1) ? sj1 : sj0;
          const float out = (val * c + sgn * prt * s) * qs;
          dst[rowoff + n * 16 + la] = f2bf(out);
        }
        {  // angle += invf (both parities)
          const float nc0 = cj0 * c1_0 - sj0 * s1_0, ns0 = sj0 * c1_0 + cj0 * s1_0;
          cj0 = nc0; sj0 = ns0;
          const float nc1 = cj1 * c1_1 - sj1 * s1_1, ns1 = sj1 * c1_1 + cj1 * s1_1;
          cj1 = nc1; sj1 = ns1;
        }
      }
      {  // angle += 16*invf (both parities)
        const float nc0 = cm0 * c16_0 - sm0 * s16_0, ns0 = sm0 * c16_0 + cm0 * s16_0;
        cm0 = nc0; sm0 = ns0;
        const float nc1 = cm1 * c16_1 - sm1 * s16_1, ns1 = sm1 * c16_1 + cm1 * s16_1;
        cm1 = nc1; sm1 = ns1;
      }
    }
    return;
  }

#pragma unroll
  for (int m = 0; m < MR; ++m)
#pragma unroll
    for (int n = 0; n < 4; ++n)
#pragma unroll
      for (int j = 0; j < 4; ++j) {
        const int row = m0 + wr + m * 16 + lb * 4 + j;
        const int col = n0 + wc + n * 16 + la;
        if (MODE == 1)
          ((float*)Cout)[(size_t)row * N + col] = acc[m][n][j];
        else
          ((u16*)Cout)[(size_t)row * N + col] = f2bf(acc[m][n][j]);
      }
}

// ---------------- flash attention (causal): R10 known-good (K+V in LDS) ----------------
// 1024 blocks x 4 waves; block = bh plane + one 64-row band (4 strips). Heavy bands first.
// K/V staged to LDS (double-buffered, gload_lds w=16, XOR pre-swizzled source, K
// sigma-permuted). Swapped QK^T: lane la owns q-row q0+la; P lane-local for PV.
__global__ __launch_bounds__(256) void attn_kernel(const u16* __restrict__ Q, const u16* __restrict__ K,
                                                   const u16* __restrict__ Vt, u16* __restrict__ Y) {
  const int L = blockIdx.y * 32 + blockIdx.x;  // 0..1023
  const int xcd = L & 7, slot = L >> 3;        // linear id % 8 = XCD; 4 bh planes per XCD
  const int bh = xcd * 4 + (slot & 3);
  const int beta = 31 - (slot >> 2);           // band index 0..31, heavy first
  const int b = bh >> 4, h = bh & 15;
  const int wave = threadIdx.x >> 6, lane = threadIdx.x & 63;
  const int la = lane & 15, lb = lane >> 4;
  const int q0 = beta * 64 + wave * 16;  // this wave's 16-row strip
  const int NT = beta + 1;               // kv tiles for the whole band

  __shared__ __align__(16) u16 KV[2][2][4096];  // [buf][K/V][64x64] (swizzled; K sigma-permuted)

  const size_t plane = (size_t)bh * (2048 * 64);
  const char* Kb = (const char*)(K + plane);
  const char* Vb = (const char*)(Vt + plane);

  auto stage = [&](int buf, int kt) {
#pragma unroll
    for (int it = 0; it < 2; ++it) {
      const int ci = it * 256 + wave * 64 + lane;          // 16B chunk id 0..511
      const int row = ci >> 3;                             // LDS tile row 0..63
      const int cbs = ((ci & 7) * 16) ^ ((row & 7) << 4);  // pre-swizzled source col byte
      const int n2 = row >> 4, rho = row & 15;
      const int srow = ((n2 & 1) << 5) + ((rho >> 2) << 3) + ((n2 >> 1) << 2) + (rho & 3);
      gload_lds16(Kb + (size_t)(kt * 64 + srow) * 128 + cbs,
                  (char*)&KV[buf][0][0] + it * 4096 + wave * 1024);
      gload_lds16(Vb + (size_t)row * 4096 + (size_t)kt * 128 + cbs,
                  (char*)&KV[buf][1][0] + it * 4096 + wave * 1024);
    }
  };

  stage(0, 0);

  bf16x8 qf[2];
#pragma unroll
  for (int s = 0; s < 2; ++s)
    qf[s] = *(const bf16x8*)(Q + plane + (size_t)(q0 + la) * 64 + s * 32 + lb * 8);

  f32x4 o[4] = {};
  float mreg = -1.0e30f;
  float plr = 0.f;

  // deswizzled u16 column index within a row, per s (32-col sub-block)
  const int x0 = (la & 7) << 4;
  const int cu0 = ((lb * 16) ^ x0) >> 1;
  const int cu1 = ((64 + lb * 16) ^ x0) >> 1;

  __syncthreads();
  int buf = 0;
  for (int kt = 0; kt < NT; ++kt) {
    if (kt + 1 < NT) stage(buf ^ 1, kt + 1);
    const u16* Kc = KV[buf][0];
    const u16* Vc = KV[buf][1];

    bf16x8 kf[2][4];
#pragma unroll
    for (int n = 0; n < 4; ++n) {
      kf[0][n] = *(const bf16x8*)&Kc[(n * 16 + la) * 64 + cu0];
      kf[1][n] = *(const bf16x8*)&Kc[(n * 16 + la) * 64 + cu1];
    }

    // ---- swapped QK^T ----
    const int rowq = q0 + la;  // this lane's q-row
    f32x4 sa[4] = {};
    __builtin_amdgcn_s_setprio(1);
#pragma unroll
    for (int s = 0; s < 2; ++s)
#pragma unroll
      for (int n = 0; n < 4; ++n)
        sa[n] = __builtin_amdgcn_mfma_f32_16x16x32_bf16(kf[s][n], qf[s], sa[n], 0, 0, 0);
    __builtin_amdgcn_s_setprio(0);
    // lane holds S[rowq][kt*64 + sig(n, lb*4+j)], sig = (n&1)*32 + lb*8 + (n>>1)*4 + j
    if (kt == NT - 1) {  // diagonal tile: causal mask
#pragma unroll
      for (int n = 0; n < 4; ++n)
#pragma unroll
        for (int j = 0; j < 4; ++j) {
          const int col = kt * 64 + ((n & 1) << 5) + (lb << 3) + ((n >> 1) << 2) + j;
          if (col > rowq) sa[n][j] = -1.0e30f;
        }
    }
    // ---- per-lane softmax (defer-max) ----
    float mn_[4];
#pragma unroll
    for (int n = 0; n < 4; ++n)
      mn_[n] = fmaxf(fmaxf(sa[n][0], sa[n][1]), fmaxf(sa[n][2], sa[n][3]));
    const float lmax = fmaxf(fmaxf(mn_[0], mn_[1]), fmaxf(mn_[2], mn_[3]));
    if (__any(lmax > mreg + 8.0f)) {
      float v = fmaxf(lmax, __shfl_xor(lmax, 16));
      v = fmaxf(v, __shfl_xor(v, 32));
      const float mn = fmaxf(mreg, v);
      const float al = __builtin_amdgcn_exp2f(mreg - mn);
      plr *= al;
      mreg = mn;
      float alj[4];
#pragma unroll
      for (int j = 0; j < 4; ++j) alj[j] = __shfl(al, lb * 4 + j);
#pragma unroll
      for (int n = 0; n < 4; ++n)
#pragma unroll
        for (int j = 0; j < 4; ++j) o[n][j] *= alj[j];
    }
    u32 w[4][2];
    float ps = 0.f;
#pragma unroll
    for (int n = 0; n < 4; ++n) {
      const float p0 = __builtin_amdgcn_exp2f(sa[n][0] - mreg);
      const float p1 = __builtin_amdgcn_exp2f(sa[n][1] - mreg);
      const float p2 = __builtin_amdgcn_exp2f(sa[n][2] - mreg);
      const float p3 = __builtin_amdgcn_exp2f(sa[n][3] - mreg);
      ps += (p0 + p1) + (p2 + p3);
      w[n][0] = (u32)f2bf(p0) | ((u32)f2bf(p1) << 16);
      w[n][1] = (u32)f2bf(p2) | ((u32)f2bf(p3) << 16);
    }
    plr += ps;
    bf16x8 paf[2];
    paf[0] = __builtin_bit_cast(bf16x8, (u32x4){w[0][0], w[0][1], w[2][0], w[2][1]});
    paf[1] = __builtin_bit_cast(bf16x8, (u32x4){w[1][0], w[1][1], w[3][0], w[3][1]});

    // ---- PV (P lane-local in A-fragment layout) ----
    bf16x8 vf[2][4];
#pragma unroll
    for (int n = 0; n < 4; ++n) {
      vf[0][n] = *(const bf16x8*)&Vc[(n * 16 + la) * 64 + cu0];
      vf[1][n] = *(const bf16x8*)&Vc[(n * 16 + la) * 64 + cu1];
    }
    __builtin_amdgcn_s_setprio(1);
#pragma unroll
    for (int n = 0; n < 4; ++n)
#pragma unroll
      for (int s = 0; s < 2; ++s)
        o[n] = __builtin_amdgcn_mfma_f32_16x16x32_bf16(paf[s], vf[s][n], o[n], 0, 0, 0);
    __builtin_amdgcn_s_setprio(0);

    __syncthreads();
    buf ^= 1;
  }

  // ---- epilogue: 2-step row-sum reduce, shfl rinv to o-rows, write ----
  float ls = plr;
  ls += __shfl_xor(ls, 16);
  ls += __shfl_xor(ls, 32);
  const float rinv = __builtin_amdgcn_rcpf(ls);
  float rj[4];
#pragma unroll
  for (int j = 0; j < 4; ++j) rj[j] = __shfl(rinv, lb * 4 + j);
#pragma unroll
  for (int n = 0; n < 4; ++n)
#pragma unroll
    for (int j = 0; j < 4; ++j) {
      const int t = q0 + lb * 4 + j;
      const int c = h * 64 + n * 16 + la;
      Y[((size_t)b * 2048 + t) * 1024 + c] = f2bf(o[n][j] * rj[j]);
    }
}

extern "C" void kernel_launch(void* const* d_in, const int* in_sizes, int n_in, void* d_out,
                              int out_size, void* d_ws, size_t ws_size, hipStream_t stream) {
  (void)in_sizes; (void)n_in; (void)out_size; (void)ws_size;
  const float* x = (const float*)d_in[0];
  const float* w_qkv = (const float*)d_in[1];
  const float* w_proj = (const float*)d_in[2];
  char* ws = (char*)d_ws;
  // workspace layout (bytes), total 40 MiB
  u16* xb     = (u16*)(ws);             // 4096*1024 bf16  (8 MiB)  -- reused as y later
  u16* wqkvT  = (u16*)(ws + 8388608);   // 3072*1024       (6 MiB)
  u16* wprojT = (u16*)(ws + 14680064);  // 1024*1024       (2 MiB)
  u16* q      = (u16*)(ws + 16777216);  // 32*2048*64      (8 MiB)
  u16* k      = (u16*)(ws + 25165824);  // 32*2048*64      (8 MiB)
  u16* vt     = (u16*)(ws + 33554432);  // 32*64*2048      (8 MiB)
  u16* y      = xb;                     // alias: xb dead after GEMM1

  prep_kernel<<<dim3(5120), dim3(256), 0, stream>>>(x, xb, w_qkv, wqkvT, w_proj, wprojT);
  gemm_bt<128, 2><<<dim3(32, 24), dim3(256), 0, stream>>>(xb, wqkvT, nullptr, 4096, 3072, 1024,
                                                          q, k, vt);
  attn_kernel<<<dim3(32, 32), dim3(256), 0, stream>>>(q, k, vt, y);
  gemm_bt<64, 1><<<dim3(64, 8), dim3(256), 0, stream>>>(y, wprojT, d_out, 4096, 1024, 1024,
                                                        nullptr, nullptr, nullptr);
}

// Round 18
// 100.915 us; speedup vs baseline: 1.1322x; 1.0309x over previous
//
#include <hip/hip_runtime.h>
#include <hip/hip_bf16.h>

typedef unsigned short u16;
typedef unsigned int u32;
typedef __attribute__((ext_vector_type(8))) __bf16 bf16x8;
typedef __attribute__((ext_vector_type(4))) float f32x4;
typedef __attribute__((ext_vector_type(4))) u16 u16x4;
typedef __attribute__((ext_vector_type(4))) u32 u32x4;

__device__ __forceinline__ u16 f2bf(float f) {
  return __builtin_bit_cast(u16, (__bf16)f);  // native RNE cvt
}

__device__ __forceinline__ void gload_lds16(const void* g, void* l) {
  __builtin_amdgcn_global_load_lds((const __attribute__((address_space(1))) void*)g,
                                   (__attribute__((address_space(3))) void*)l, 16, 0, 0);
}

// ---------------- fused prep: fp32->bf16 cvt of x + both weight transposes ----------------
__global__ __launch_bounds__(256) void prep_kernel(const float* __restrict__ x, u16* __restrict__ xb,
                                                   const float* __restrict__ wq, u16* __restrict__ wqT,
                                                   const float* __restrict__ wp, u16* __restrict__ wpT) {
  const int bid = blockIdx.x;
  const int tid = threadIdx.x;
  if (bid < 4096) {  // cvt x
    const int i = (bid * 256 + tid) * 4;
    const float4 v = *(const float4*)(x + i);
    u16x4 r = {f2bf(v.x), f2bf(v.y), f2bf(v.z), f2bf(v.w)};
    *(u16x4*)(xb + i) = r;
    return;
  }
  __shared__ u16 tile[64][65];
  const float* w;
  u16* wt;
  int K, N, n0, k0;
  if (bid < 4864) {
    const int id = bid - 4096;  // transpose w_qkv (48 x 16 tiles)
    w = wq; wt = wqT; K = 1024; N = 3072;
    n0 = (id % 48) * 64; k0 = (id / 48) * 64;
  } else {
    const int id = bid - 4864;  // transpose w_proj (16 x 16 tiles)
    w = wp; wt = wpT; K = 1024; N = 1024;
    n0 = (id % 16) * 64; k0 = (id / 16) * 64;
  }
#pragma unroll
  for (int it = 0; it < 16; ++it) {
    const int idx = it * 256 + tid;
    const int r = idx >> 6, c = idx & 63;
    tile[r][c] = f2bf(w[(size_t)(k0 + r) * N + n0 + c]);
  }
  __syncthreads();
#pragma unroll
  for (int it = 0; it < 16; ++it) {
    const int idx = it * 256 + tid;
    const int r2 = idx >> 6, c2 = idx & 63;
    wt[(size_t)(n0 + r2) * K + k0 + c2] = tile[c2][r2];
  }
}

// ---------------- bf16 GEMM: C[M][N] = A[M][K] * Bt[N][K]^T ----------------
// m97 structure + prefetch double-buffer + XCD-chunked swizzle.
// MODE 1: f32 out (final projection). MODE 2 (BM=128 only): fused RoPE epilogue.
// Q/K epilogue n-INNERMOST (full 128B line per (m,j) back-to-back -> write combining,
// R17: -2.3us). Trig = two parity recurrences. V = direct u16x4 scatter. VGPR 80 /
// 5 blocks/CU — measured cliff; do not raise register pressure here (R13-R15).
template <int BM, int MODE>
__global__ __launch_bounds__(256) void gemm_bt(const u16* __restrict__ A, const u16* __restrict__ Bt,
                                               void* __restrict__ Cout, int M, int N, int K,
                                               u16* __restrict__ Qo, u16* __restrict__ Ko,
                                               u16* __restrict__ Vto) {
  constexpr int MR = (BM == 128) ? 4 : 2;  // m-fragments per wave
  __shared__ u16 As[2][BM * 32];
  __shared__ u16 Bs[2][128 * 32];
  const int tid = threadIdx.x;
  const int wave = tid >> 6;
  const int lane = tid & 63;
  const int la = lane & 15, lb = lane >> 4;
  const int nwg = gridDim.x * gridDim.y;
  int lid = blockIdx.y * gridDim.x + blockIdx.x;
  lid = (lid & 7) * (nwg >> 3) + (lid >> 3);
  const int m0 = (lid % gridDim.x) * BM, n0 = (lid / gridDim.x) * 128;
  const int wr = (wave >> 1) * (BM / 2), wc = (wave & 1) * 64;
  const int srow = lane >> 2;       // 0..15
  const int scol = (lane & 3) * 8;  // 0,8,16,24
  const int c0 = wave * 2;

  auto stage = [&](int bb, int k0) {
    if (BM == 128) {
#pragma unroll
      for (int c2 = 0; c2 < 2; ++c2) {
        const int c = c0 + c2;
        const int row = c * 16 + srow;
        gload_lds16(A + (size_t)(m0 + row) * K + k0 + scol, As[bb] + c * 512);
      }
    } else {
      const int row = wave * 16 + srow;
      gload_lds16(A + (size_t)(m0 + row) * K + k0 + scol, As[bb] + wave * 512);
    }
#pragma unroll
    for (int c2 = 0; c2 < 2; ++c2) {
      const int c = c0 + c2;
      const int row = c * 16 + srow;
      gload_lds16(Bt + (size_t)(n0 + row) * K + k0 + scol, Bs[bb] + c * 512);
    }
  };

  f32x4 acc[MR][4] = {};
  const int nk = K >> 5;
  stage(0, 0);
  __syncthreads();
  int cur = 0;
  for (int t = 0; t < nk; ++t) {
    if (t + 1 < nk) stage(cur ^ 1, (t + 1) * 32);  // prefetch under compute
    bf16x8 af[MR], bfr[4];
#pragma unroll
    for (int m = 0; m < MR; ++m) af[m] = *(const bf16x8*)&As[cur][(wr + m * 16 + la) * 32 + lb * 8];
#pragma unroll
    for (int n = 0; n < 4; ++n) bfr[n] = *(const bf16x8*)&Bs[cur][(wc + n * 16 + la) * 32 + lb * 8];
#pragma unroll
    for (int m = 0; m < MR; ++m)
#pragma unroll
      for (int n = 0; n < 4; ++n)
        acc[m][n] = __builtin_amdgcn_mfma_f32_16x16x32_bf16(af[m], bfr[n], acc[m][n], 0, 0, 0);
    __syncthreads();  // drains prefetch vmcnt + guards buffer reuse
    cur ^= 1;
  }

  if (MODE == 2) {
    // Fused RoPE + reshape + V-transpose epilogue.
    const float NEG = -0.41524101186f;  // -log2(10000)/32
    const float QSC = 0.18033688011f;   // 0.125 * log2(e)
    const int reg = n0 >> 10;           // 0=q 1=k 2=v (uniform for the whole 128-col block)
    if (reg == 2) {
      // ---- V: direct u16x4 scatter (lines completed per (n, m-set) — measured OK) ----
#pragma unroll
      for (int n = 0; n < 4; ++n) {
        const int c = n0 + wc + n * 16 + la;
        const int d = c & 63;
        const int h = (c & 1023) >> 6;
#pragma unroll
        for (int m = 0; m < MR; ++m) {
          const int t0 = m0 + wr + m * 16 + lb * 4;
          const int bb = t0 >> 11, tl0 = t0 & 2047;
          u16x4 pv;
#pragma unroll
          for (int j = 0; j < 4; ++j) pv[j] = f2bf(acc[m][n][j]);
          *(u16x4*)(Vto + ((size_t)(bb * 16 + h) * 64 + d) * 2048 + tl0) = pv;
        }
      }
      return;
    }
    // ---- Q/K: RoPE, n-innermost store order (full-line write combining) ----
    u16* dst = (reg == 0) ? Qo : Ko;
    const float qs = (reg == 0) ? QSC : 1.0f;
    const float sgn = (la & 1) ? 1.0f : -1.0f;  // rot[2i]=-x[2i+1], rot[2i+1]=x[2i]
    const int h = ((n0 & 1023) >> 6) + (wc >> 6);  // per-wave constant head
    const int tb = m0 + wr + lb * 4;
    const int bb = tb >> 11;
    const int tlb = tb & 2047;
    const size_t plane = (size_t)(bb * 16 + h) * 2048;
    const float invf0 = exp2f(NEG * (float)la);
    const float invf1 = exp2f(NEG * (float)(16 + la));
    float s1_0, c1_0, s1_1, c1_1, s16_0, c16_0, s16_1, c16_1, sm0, cm0, sm1, cm1;
    sincosf(invf0, &s1_0, &c1_0);
    sincosf(invf1, &s1_1, &c1_1);
    sincosf(16.0f * invf0, &s16_0, &c16_0);
    sincosf(16.0f * invf1, &s16_1, &c16_1);
    sincosf((float)tlb * invf0, &sm0, &cm0);
    sincosf((float)tlb * invf1, &sm1, &cm1);
#pragma unroll
    for (int m = 0; m < MR; ++m) {
      float cj0 = cm0, sj0 = sm0, cj1 = cm1, sj1 = sm1;
#pragma unroll
      for (int j = 0; j < 4; ++j) {
        const size_t rowoff = (plane + tlb + m * 16 + j) * 64;
#pragma unroll
        for (int n = 0; n < 4; ++n) {
          const float val = acc[m][n][j];
          const float prt = __shfl_xor(val, 1);  // rotation partner (adjacent col = adjacent lane)
          const float c = (n & 1) ? cj1 : cj0;
          const float s = (n & 1) ? sj1 : sj0;
          const float out = (val * c + sgn * prt * s) * qs;
          dst[rowoff + n * 16 + la] = f2bf(out);
        }
        {  // angle += invf (both parities)
          const float nc0 = cj0 * c1_0 - sj0 * s1_0, ns0 = sj0 * c1_0 + cj0 * s1_0;
          cj0 = nc0; sj0 = ns0;
          const float nc1 = cj1 * c1_1 - sj1 * s1_1, ns1 = sj1 * c1_1 + cj1 * s1_1;
          cj1 = nc1; sj1 = ns1;
        }
      }
      {  // angle += 16*invf (both parities)
        const float nc0 = cm0 * c16_0 - sm0 * s16_0, ns0 = sm0 * c16_0 + cm0 * s16_0;
        cm0 = nc0; sm0 = ns0;
        const float nc1 = cm1 * c16_1 - sm1 * s16_1, ns1 = sm1 * c16_1 + cm1 * s16_1;
        cm1 = nc1; sm1 = ns1;
      }
    }
    return;
  }

#pragma unroll
  for (int m = 0; m < MR; ++m)
#pragma unroll
    for (int n = 0; n < 4; ++n)
#pragma unroll
      for (int j = 0; j < 4; ++j) {
        const int row = m0 + wr + m * 16 + lb * 4 + j;
        const int col = n0 + wc + n * 16 + la;
        if (MODE == 1)
          ((float*)Cout)[(size_t)row * N + col] = acc[m][n][j];
        else
          ((u16*)Cout)[(size_t)row * N + col] = f2bf(acc[m][n][j]);
      }
}

// ---------------- flash attention (causal): R10 structure + CU-balanced band permutation ----------------
// 1024 blocks x 4 waves; block = bh plane + one 64-row band (4 strips).
// R18 change: band chosen via balanced permutation — under round-robin dispatch
// (CU c hosts blocks {c, c+256k}), each CU's 4 bands are {31-g, 16+g, 15-g, g}
// (sum 62 -> NT sum 66 = mean) instead of {j, j+8, j+16, j+24} (NT sum 52..80).
// Pure bijection: total work unchanged; worst-case neutral if dispatch model wrong.
__global__ __launch_bounds__(256) void attn_kernel(const u16* __restrict__ Q, const u16* __restrict__ K,
                                                   const u16* __restrict__ Vt, u16* __restrict__ Y) {
  const int L = blockIdx.y * 32 + blockIdx.x;  // 0..1023
  const int xcd = L & 7, slot = L >> 3;        // linear id % 8 = XCD; 4 bh planes per XCD
  const int bh = xcd * 4 + (slot & 3);
  const int cidx = slot >> 2;                  // 0..31 band-order index
  const int g = cidx & 7, p = cidx >> 3;
  const int beta = (p == 0) ? (31 - g) : (p == 1) ? (16 + g) : (p == 2) ? (15 - g) : g;
  const int b = bh >> 4, h = bh & 15;
  const int wave = threadIdx.x >> 6, lane = threadIdx.x & 63;
  const int la = lane & 15, lb = lane >> 4;
  const int q0 = beta * 64 + wave * 16;  // this wave's 16-row strip
  const int NT = beta + 1;               // kv tiles for the whole band

  __shared__ __align__(16) u16 KV[2][2][4096];  // [buf][K/V][64x64] (swizzled; K sigma-permuted)

  const size_t plane = (size_t)bh * (2048 * 64);
  const char* Kb = (const char*)(K + plane);
  const char* Vb = (const char*)(Vt + plane);

  auto stage = [&](int buf, int kt) {
#pragma unroll
    for (int it = 0; it < 2; ++it) {
      const int ci = it * 256 + wave * 64 + lane;          // 16B chunk id 0..511
      const int row = ci >> 3;                             // LDS tile row 0..63
      const int cbs = ((ci & 7) * 16) ^ ((row & 7) << 4);  // pre-swizzled source col byte
      const int n2 = row >> 4, rho = row & 15;
      const int srow = ((n2 & 1) << 5) + ((rho >> 2) << 3) + ((n2 >> 1) << 2) + (rho & 3);
      gload_lds16(Kb + (size_t)(kt * 64 + srow) * 128 + cbs,
                  (char*)&KV[buf][0][0] + it * 4096 + wave * 1024);
      gload_lds16(Vb + (size_t)row * 4096 + (size_t)kt * 128 + cbs,
                  (char*)&KV[buf][1][0] + it * 4096 + wave * 1024);
    }
  };

  stage(0, 0);

  bf16x8 qf[2];
#pragma unroll
  for (int s = 0; s < 2; ++s)
    qf[s] = *(const bf16x8*)(Q + plane + (size_t)(q0 + la) * 64 + s * 32 + lb * 8);

  f32x4 o[4] = {};
  float mreg = -1.0e30f;
  float plr = 0.f;

  // deswizzled u16 column index within a row, per s (32-col sub-block)
  const int x0 = (la & 7) << 4;
  const int cu0 = ((lb * 16) ^ x0) >> 1;
  const int cu1 = ((64 + lb * 16) ^ x0) >> 1;

  __syncthreads();
  int buf = 0;
  for (int kt = 0; kt < NT; ++kt) {
    if (kt + 1 < NT) stage(buf ^ 1, kt + 1);
    const u16* Kc = KV[buf][0];
    const u16* Vc = KV[buf][1];

    bf16x8 kf[2][4];
#pragma unroll
    for (int n = 0; n < 4; ++n) {
      kf[0][n] = *(const bf16x8*)&Kc[(n * 16 + la) * 64 + cu0];
      kf[1][n] = *(const bf16x8*)&Kc[(n * 16 + la) * 64 + cu1];
    }

    // ---- swapped QK^T ----
    const int rowq = q0 + la;  // this lane's q-row
    f32x4 sa[4] = {};
    __builtin_amdgcn_s_setprio(1);
#pragma unroll
    for (int s = 0; s < 2; ++s)
#pragma unroll
      for (int n = 0; n < 4; ++n)
        sa[n] = __builtin_amdgcn_mfma_f32_16x16x32_bf16(kf[s][n], qf[s], sa[n], 0, 0, 0);
    __builtin_amdgcn_s_setprio(0);
    // lane holds S[rowq][kt*64 + sig(n, lb*4+j)], sig = (n&1)*32 + lb*8 + (n>>1)*4 + j
    if (kt == NT - 1) {  // diagonal tile: causal mask
#pragma unroll
      for (int n = 0; n < 4; ++n)
#pragma unroll
        for (int j = 0; j < 4; ++j) {
          const int col = kt * 64 + ((n & 1) << 5) + (lb << 3) + ((n >> 1) << 2) + j;
          if (col > rowq) sa[n][j] = -1.0e30f;
        }
    }
    // ---- per-lane softmax (defer-max) ----
    float mn_[4];
#pragma unroll
    for (int n = 0; n < 4; ++n)
      mn_[n] = fmaxf(fmaxf(sa[n][0], sa[n][1]), fmaxf(sa[n][2], sa[n][3]));
    const float lmax = fmaxf(fmaxf(mn_[0], mn_[1]), fmaxf(mn_[2], mn_[3]));
    if (__any(lmax > mreg + 8.0f)) {
      float v = fmaxf(lmax, __shfl_xor(lmax, 16));
      v = fmaxf(v, __shfl_xor(v, 32));
      const float mn = fmaxf(mreg, v);
      const float al = __builtin_amdgcn_exp2f(mreg - mn);
      plr *= al;
      mreg = mn;
      float alj[4];
#pragma unroll
      for (int j = 0; j < 4; ++j) alj[j] = __shfl(al, lb * 4 + j);
#pragma unroll
      for (int n = 0; n < 4; ++n)
#pragma unroll
        for (int j = 0; j < 4; ++j) o[n][j] *= alj[j];
    }
    u32 w[4][2];
    float ps = 0.f;
#pragma unroll
    for (int n = 0; n < 4; ++n) {
      const float p0 = __builtin_amdgcn_exp2f(sa[n][0] - mreg);
      const float p1 = __builtin_amdgcn_exp2f(sa[n][1] - mreg);
      const float p2 = __builtin_amdgcn_exp2f(sa[n][2] - mreg);
      const float p3 = __builtin_amdgcn_exp2f(sa[n][3] - mreg);
      ps += (p0 + p1) + (p2 + p3);
      w[n][0] = (u32)f2bf(p0) | ((u32)f2bf(p1) << 16);
      w[n][1] = (u32)f2bf(p2) | ((u32)f2bf(p3) << 16);
    }
    plr += ps;
    bf16x8 paf[2];
    paf[0] = __builtin_bit_cast(bf16x8, (u32x4){w[0][0], w[0][1], w[2][0], w[2][1]});
    paf[1] = __builtin_bit_cast(bf16x8, (u32x4){w[1][0], w[1][1], w[3][0], w[3][1]});

    // ---- PV (P lane-local in A-fragment layout) ----
    bf16x8 vf[2][4];
#pragma unroll
    for (int n = 0; n < 4; ++n) {
      vf[0][n] = *(const bf16x8*)&Vc[(n * 16 + la) * 64 + cu0];
      vf[1][n] = *(const bf16x8*)&Vc[(n * 16 + la) * 64 + cu1];
    }
    __builtin_amdgcn_s_setprio(1);
#pragma unroll
    for (int n = 0; n < 4; ++n)
#pragma unroll
      for (int s = 0; s < 2; ++s)
        o[n] = __builtin_amdgcn_mfma_f32_16x16x32_bf16(paf[s], vf[s][n], o[n], 0, 0, 0);
    __builtin_amdgcn_s_setprio(0);

    __syncthreads();
    buf ^= 1;
  }

  // ---- epilogue: 2-step row-sum reduce, shfl rinv to o-rows, write ----
  float ls = plr;
  ls += __shfl_xor(ls, 16);
  ls += __shfl_xor(ls, 32);
  const float rinv = __builtin_amdgcn_rcpf(ls);
  float rj[4];
#pragma unroll
  for (int j = 0; j < 4; ++j) rj[j] = __shfl(rinv, lb * 4 + j);
#pragma unroll
  for (int n = 0; n < 4; ++n)
#pragma unroll
    for (int j = 0; j < 4; ++j) {
      const int t = q0 + lb * 4 + j;
      const int c = h * 64 + n * 16 + la;
      Y[((size_t)b * 2048 + t) * 1024 + c] = f2bf(o[n][j] * rj[j]);
    }
}

extern "C" void kernel_launch(void* const* d_in, const int* in_sizes, int n_in, void* d_out,
                              int out_size, void* d_ws, size_t ws_size, hipStream_t stream) {
  (void)in_sizes; (void)n_in; (void)out_size; (void)ws_size;
  const float* x = (const float*)d_in[0];
  const float* w_qkv = (const float*)d_in[1];
  const float* w_proj = (const float*)d_in[2];
  char* ws = (char*)d_ws;
  // workspace layout (bytes), total 40 MiB
  u16* xb     = (u16*)(ws);             // 4096*1024 bf16  (8 MiB)  -- reused as y later
  u16* wqkvT  = (u16*)(ws + 8388608);   // 3072*1024       (6 MiB)
  u16* wprojT = (u16*)(ws + 14680064);  // 1024*1024       (2 MiB)
  u16* q      = (u16*)(ws + 16777216);  // 32*2048*64      (8 MiB)
  u16* k      = (u16*)(ws + 25165824);  // 32*2048*64      (8 MiB)
  u16* vt     = (u16*)(ws + 33554432);  // 32*64*2048      (8 MiB)
  u16* y      = xb;                     // alias: xb dead after GEMM1

  prep_kernel<<<dim3(5120), dim3(256), 0, stream>>>(x, xb, w_qkv, wqkvT, w_proj, wprojT);
  gemm_bt<128, 2><<<dim3(32, 24), dim3(256), 0, stream>>>(xb, wqkvT, nullptr, 4096, 3072, 1024,
                                                          q, k, vt);
  attn_kernel<<<dim3(32, 32), dim3(256), 0, stream>>>(q, k, vt, y);
  gemm_bt<64, 1><<<dim3(64, 8), dim3(256), 0, stream>>>(y, wprojT, d_out, 4096, 1024, 1024,
                                                        nullptr, nullptr, nullptr);
}